// Round 11
// baseline (1498.692 us; speedup 1.0000x reference)
//
#include <hip/hip_runtime.h>
#include <hip/hip_bf16.h>
#include <math.h>

// Problem constants (B=4, S=2048, D=1024, H=2048, E=8)
#define M_TOK 8192   // B*S
#define N_H   2048   // H
#define K_D   1024   // D
#define N_E   8

typedef __bf16 bf16x8 __attribute__((ext_vector_type(8)));
typedef __bf16 bf16x4 __attribute__((ext_vector_type(4)));
typedef float  f32x4  __attribute__((ext_vector_type(4)));

__device__ inline f32x4 mfma16(bf16x8 a, bf16x8 b, f32x4 c) {
  return __builtin_amdgcn_mfma_f32_16x16x32_bf16(a, b, c, 0, 0, 0);
}

__device__ inline void load16_lds(const void* g, void* l) {
  __builtin_amdgcn_global_load_lds(
      (const __attribute__((address_space(1))) void*)g,
      (__attribute__((address_space(3))) void*)l, 16, 0, 0);
}

// ---------------------------------------------------------------- f32 -> bf16
__global__ __launch_bounds__(256) void cvt_kernel(const float* __restrict__ src,
                                                  __bf16* __restrict__ dst,
                                                  int n4) {
  int i = blockIdx.x * blockDim.x + threadIdx.x;
  const int stride = gridDim.x * blockDim.x;
  for (; i < n4; i += stride) {
    float4 v = ((const float4*)src)[i];
    bf16x4 o = {(__bf16)v.x, (__bf16)v.y, (__bf16)v.z, (__bf16)v.w};
    *(bf16x4*)(dst + (size_t)i * 4) = o;
  }
}

// ------------------------------------------- gate probs + X f32->bf16 (fused)
__global__ __launch_bounds__(256) void gate_kernel(const float* __restrict__ X,
                                                   const float* __restrict__ Wg,
                                                   const float* __restrict__ bg,
                                                   float* __restrict__ gate,
                                                   __bf16* __restrict__ Xb) {
  const int tid = threadIdx.x;
  const int lane = tid & 63;
  const int wv = tid >> 6;
  const int token = blockIdx.x * 4 + wv;
  const float* xrow = X + (size_t)token * K_D;

  float xr[16];
#pragma unroll
  for (int i = 0; i < 16; ++i) xr[i] = xrow[lane + i * 64];

#pragma unroll
  for (int i = 0; i < 16; ++i)
    Xb[(size_t)token * K_D + lane + i * 64] = (__bf16)xr[i];

  float l[N_E];
#pragma unroll
  for (int e = 0; e < N_E; ++e) {
    const float* wrow = Wg + e * K_D;
    float s = 0.f;
#pragma unroll
    for (int i = 0; i < 16; ++i) s += xr[i] * wrow[lane + i * 64];
#pragma unroll
    for (int off = 32; off > 0; off >>= 1) s += __shfl_xor(s, off);
    l[e] = s + bg[e];
  }
  float mx = l[0];
#pragma unroll
  for (int e = 1; e < N_E; ++e) mx = fmaxf(mx, l[e]);
  float p[N_E], den = 0.f;
#pragma unroll
  for (int e = 0; e < N_E; ++e) { p[e] = expf(l[e] - mx); den += p[e]; }
  const float inv = 1.f / den;
  if (lane == 0) {
#pragma unroll
    for (int e = 0; e < N_E; ++e) gate[(size_t)token * N_E + e] = p[e] * inv;
  }
}

// ------------------------------------------------------------------- main MoE
// r11 = r5's verified schedule (2-buf, counted vmcnt(6), pure phases) with
// gS/bS LDS tiles REMOVED: LDS 57.3 -> 48.0 KB per block, so 3 blocks/CU fit
// (was LDS-limited to 2). 12 waves/CU give the cross-block phase cover the
// 2-block version lacked (measured: MFMA 1242 + LDS 1152 cy/step ran in
// series). EPI reads gate/be straight from global (4 KB L1/L2-resident
// panels, 4 EPIs total). Register check: 128 VGPR x 3 waves/SIMD = 384<=512.
__global__ __launch_bounds__(256, 3) void moe_main(
    const __bf16* __restrict__ Xb, const __bf16* __restrict__ Wb,
    const float* __restrict__ gate, const float* __restrict__ be,
    float* __restrict__ out) {
  __shared__ __bf16 As[2][128 * 32];   // 16 KB (double-buffered)
  __shared__ __bf16 Bs[2][256 * 32];   // 32 KB (double-buffered, 2 experts)

  const int tid = threadIdx.x;
  const int lane = tid & 63;
  const int wv = tid >> 6;
  const int wr = wv >> 1, wn = wv & 1;
  const int row0 = blockIdx.x * 128;
  const int col0 = blockIdx.y * 128;

  // Staging geometry: thread stages 16B; LDS row rA = tid>>2, chunk tid&3.
  const int rA = tid >> 2;
  const int kk = (tid & 3) * 8;
  const __bf16* aB = Xb + (size_t)(row0 + rA) * K_D + kk;
  const __bf16* bB = Wb + (size_t)(col0 + rA) * K_D + kk;

  // Fragment read bases, one per buffer parity (compile-time selected).
  const int lr = lane & 15;
  const int lk = (lane >> 4) * 8;
  const __bf16* aRd0 = &As[0][(wr * 64 + lr) * 32 + lk];
  const __bf16* aRd1 = &As[1][(wr * 64 + lr) * 32 + lk];
  const __bf16* bRd0 = &Bs[0][(wn * 64 + lr) * 32 + lk];
  const __bf16* bRd1 = &Bs[1][(wn * 64 + lr) * 32 + lk];

  f32x4 fin[4][4];
#pragma unroll
  for (int m = 0; m < 4; ++m)
#pragma unroll
    for (int h = 0; h < 4; ++h) fin[m][h] = (f32x4){0.f, 0.f, 0.f, 0.f};

  f32x4 acc[4][8];
#pragma unroll
  for (int m = 0; m < 4; ++m)
#pragma unroll
    for (int n = 0; n < 8; ++n) acc[m][n] = (f32x4){0.f, 0.f, 0.f, 0.f};

  // Stage k-step tn into buffer bufN. tn = pair*32 + kt;
  // pair stride in Wb = 2 experts * N_H * K_D = 1<<22 elems.
  auto STAGE = [&](int tn, int bufN) {
    const int k0 = (tn & 31) << 5;
    const size_t pOff = (size_t)(tn >> 5) << 22;
    const __bf16* a = aB + k0;
    load16_lds(a, &As[bufN][wv * 512]);
    load16_lds(a + (size_t)64 * K_D, &As[bufN][2048 + wv * 512]);
    const __bf16* b = bB + pOff + k0;
    load16_lds(b, &Bs[bufN][wv * 512]);
    load16_lds(b + (size_t)64 * K_D, &Bs[bufN][2048 + wv * 512]);
    load16_lds(b + (size_t)N_H * K_D, &Bs[bufN][4096 + wv * 512]);
    load16_lds(b + (size_t)(N_H + 64) * K_D, &Bs[bufN][6144 + wv * 512]);
  };

  // Pair epilogue: fin += g_e0*LR(acc_e0 + be) + g_e1*LR(acc_e1 + be); acc=0.
  // gate/be read directly from global (L1/L2-resident panels; 4 EPIs total).
  auto EPI = [&](int p) {
    const int e0 = p * 2;
#pragma unroll
    for (int m = 0; m < 4; ++m) {
#pragma unroll
      for (int j = 0; j < 4; ++j) {
        const int r = row0 + wr * 64 + m * 16 + (lane >> 4) * 4 + j;
        const float g0 = gate[(size_t)r * N_E + e0];
        const float g1 = gate[(size_t)r * N_E + e0 + 1];
#pragma unroll
        for (int h = 0; h < 4; ++h) {
          const int c = col0 + wn * 64 + h * 16 + lr;
          float v0 = acc[m][h][j] + be[(size_t)e0 * N_H + c];
          v0 = (v0 >= 0.f) ? v0 : 0.01f * v0;
          float v1 = acc[m][4 + h][j] + be[(size_t)(e0 + 1) * N_H + c];
          v1 = (v1 >= 0.f) ? v1 : 0.01f * v1;
          fin[m][h][j] += g0 * v0 + g1 * v1;
        }
      }
    }
#pragma unroll
    for (int m = 0; m < 4; ++m)
#pragma unroll
      for (int n = 0; n < 8; ++n) acc[m][n] = (f32x4){0.f, 0.f, 0.f, 0.f};
  };

  // One k-step at compile-time buffer parity. doStage: t+2 <= 127.
  auto STEP = [&](int t, const __bf16* aRd, const __bf16* bRd, int bufN,
                  bool doStage, bool lastStep) {
    if (lastStep)
      asm volatile("s_waitcnt vmcnt(0)" ::: "memory");
    else
      asm volatile("s_waitcnt vmcnt(6)" ::: "memory");  // tile t landed; t+1 in flight
    __builtin_amdgcn_s_barrier();                        // all waves: tile t ready

    bf16x8 af[4], bfr[8];
#pragma unroll
    for (int m = 0; m < 4; ++m) af[m] = *(const bf16x8*)(aRd + m * 512);
#pragma unroll
    for (int n = 0; n < 8; ++n)
      bfr[n] = *(const bf16x8*)(bRd + ((n >> 2) * 128 + (n & 3) * 16) * 32);
    asm volatile("s_waitcnt lgkmcnt(0)" ::: "memory");   // frag reads retired
    __builtin_amdgcn_sched_barrier(0);                   // rule 18: pin MFMA below
    __builtin_amdgcn_s_barrier();                        // buffer bufN free

    if (doStage) STAGE(t + 2, bufN);                     // refill under MFMA

    __builtin_amdgcn_s_setprio(1);
#pragma unroll
    for (int n = 0; n < 8; ++n)
#pragma unroll
      for (int m = 0; m < 4; ++m)
        acc[m][n] = mfma16(af[m], bfr[n], acc[m][n]);
    __builtin_amdgcn_s_setprio(0);

    if ((t & 31) == 31) EPI(t >> 5);
  };

  STAGE(0, 0);
  STAGE(1, 1);  // 12 loads in flight; no drain — first STEP waits vmcnt(6)

#pragma unroll 1
  for (int t2 = 0; t2 < 126; t2 += 2) {
    STEP(t2 + 0, aRd0, bRd0, 0, true, false);
    STEP(t2 + 1, aRd1, bRd1, 1, true, false);
  }
  STEP(126, aRd0, bRd0, 0, false, false);
  STEP(127, aRd1, bRd1, 1, false, true);

  // C write (fp32 out)
#pragma unroll
  for (int m = 0; m < 4; ++m) {
#pragma unroll
    for (int j = 0; j < 4; ++j) {
      const size_t r = (size_t)(row0 + wr * 64 + m * 16 + (lane >> 4) * 4 + j);
#pragma unroll
      for (int h = 0; h < 4; ++h) {
        out[r * N_H + col0 + wn * 64 + h * 16 + lr] = fin[m][h][j];
      }
    }
  }
}

extern "C" void kernel_launch(void* const* d_in, const int* in_sizes, int n_in,
                              void* d_out, int out_size, void* d_ws, size_t ws_size,
                              hipStream_t stream) {
  const float* X  = (const float*)d_in[0];  // [8192,1024]
  const float* Wg = (const float*)d_in[1];  // [8,1024]
  const float* bg = (const float*)d_in[2];  // [8]
  const float* We = (const float*)d_in[3];  // [8,2048,1024]
  const float* be = (const float*)d_in[4];  // [8,2048]
  float* out = (float*)d_out;               // [8192,2048]

  // Workspace layout
  char* ws = (char*)d_ws;
  __bf16* Xb   = (__bf16*)(ws);                               // 16 MB
  __bf16* Wb   = (__bf16*)(ws + (size_t)16 * 1024 * 1024);    // 32 MB
  float*  gate = (float*)(ws + (size_t)48 * 1024 * 1024);     // 256 KB

  // 1) We f32 -> bf16
  cvt_kernel<<<2048, 256, 0, stream>>>(We, Wb, (N_E * N_H * K_D) / 4);

  // 2) gate probs + X f32->bf16 (fused)
  gate_kernel<<<M_TOK / 4, 256, 0, stream>>>(X, Wg, bg, gate, Xb);

  // 3) fused expert GEMM + gate-weighted reduction
  dim3 grid(M_TOK / 128, N_H / 128);
  moe_main<<<grid, 256, 0, stream>>>(Xb, Wb, gate, be, out);
}

// Round 12
// 304.540 us; speedup vs baseline: 4.9212x; 4.9212x over previous
//
#include <hip/hip_runtime.h>
#include <hip/hip_bf16.h>
#include <math.h>

// Problem constants (B=4, S=2048, D=1024, H=2048, E=8)
#define M_TOK 8192   // B*S
#define N_H   2048   // H
#define K_D   1024   // D
#define N_E   8

typedef __bf16 bf16x8 __attribute__((ext_vector_type(8)));
typedef __bf16 bf16x4 __attribute__((ext_vector_type(4)));
typedef float  f32x4  __attribute__((ext_vector_type(4)));

__device__ inline f32x4 mfma16(bf16x8 a, bf16x8 b, f32x4 c) {
  return __builtin_amdgcn_mfma_f32_16x16x32_bf16(a, b, c, 0, 0, 0);
}

__device__ inline void load16_lds(const void* g, void* l) {
  __builtin_amdgcn_global_load_lds(
      (const __attribute__((address_space(1))) void*)g,
      (__attribute__((address_space(3))) void*)l, 16, 0, 0);
}

// ---------------------------------------------------------------- f32 -> bf16
__global__ __launch_bounds__(256) void cvt_kernel(const float* __restrict__ src,
                                                  __bf16* __restrict__ dst,
                                                  int n4) {
  int i = blockIdx.x * blockDim.x + threadIdx.x;
  const int stride = gridDim.x * blockDim.x;
  for (; i < n4; i += stride) {
    float4 v = ((const float4*)src)[i];
    bf16x4 o = {(__bf16)v.x, (__bf16)v.y, (__bf16)v.z, (__bf16)v.w};
    *(bf16x4*)(dst + (size_t)i * 4) = o;
  }
}

// ------------------------------------------- gate probs + X f32->bf16 (fused)
__global__ __launch_bounds__(256) void gate_kernel(const float* __restrict__ X,
                                                   const float* __restrict__ Wg,
                                                   const float* __restrict__ bg,
                                                   float* __restrict__ gate,
                                                   __bf16* __restrict__ Xb) {
  const int tid = threadIdx.x;
  const int lane = tid & 63;
  const int wv = tid >> 6;
  const int token = blockIdx.x * 4 + wv;
  const float* xrow = X + (size_t)token * K_D;

  float xr[16];
#pragma unroll
  for (int i = 0; i < 16; ++i) xr[i] = xrow[lane + i * 64];

#pragma unroll
  for (int i = 0; i < 16; ++i)
    Xb[(size_t)token * K_D + lane + i * 64] = (__bf16)xr[i];

  float l[N_E];
#pragma unroll
  for (int e = 0; e < N_E; ++e) {
    const float* wrow = Wg + e * K_D;
    float s = 0.f;
#pragma unroll
    for (int i = 0; i < 16; ++i) s += xr[i] * wrow[lane + i * 64];
#pragma unroll
    for (int off = 32; off > 0; off >>= 1) s += __shfl_xor(s, off);
    l[e] = s + bg[e];
  }
  float mx = l[0];
#pragma unroll
  for (int e = 1; e < N_E; ++e) mx = fmaxf(mx, l[e]);
  float p[N_E], den = 0.f;
#pragma unroll
  for (int e = 0; e < N_E; ++e) { p[e] = expf(l[e] - mx); den += p[e]; }
  const float inv = 1.f / den;
  if (lane == 0) {
#pragma unroll
    for (int e = 0; e < N_E; ++e) gate[(size_t)token * N_E + e] = p[e] * inv;
  }
}

// ------------------------------------------------------------------- main MoE
// r12: 256-token tall tile, counted-vmcnt phase pipeline (T3/T4 mechanism).
// Block = 256 tokens x 128 h-cols x 2 staged experts, 8 waves (512 thr),
// wave (wm 0..3 token-quarter, wn 0..1 h-half) -> per-wave work per phase is
// BYTE-IDENTICAL to r5's proven step: 12 ds_read_b128 + 32 MFMA, acc[4][8],
// fin[4][4], same EPI. 128 phases total (4 expert-pairs x 32 k-subs).
// LDS: 4 k-sub buffers As[4]/Bs[4] (literal indices = compile-time addrs)
// + gS/bS = 139 KB -> 1 block/CU. 4 buffers give a FULL phase of WAR slack:
//   phase sn: vmcnt(4) [sn's 4 own loads landed; sn+1's in flight]
//             s_barrier [all waves' sn loads published]  (ONE barrier/phase)
//             12 ds_read (buf sn&3); lgkmcnt(0); SGB
//             STAGE(sn+2 -> buf (sn+2)&3)   [target last read at sn-2: safe]
//             32 MFMA (setprio); EPI at pair end
// vmcnt never drains in-loop; staging bytes/FLOP halve vs r5 (taller tile).
// Registers: same budget as r5 (launch_bounds(512,2) -> 2 waves/SIMD, 256/wave).
__global__ __launch_bounds__(512, 2) void moe_main(
    const __bf16* __restrict__ Xb, const __bf16* __restrict__ Wb,
    const float* __restrict__ gate, const float* __restrict__ be,
    float* __restrict__ out) {
  __shared__ __bf16 As[4][8192];   // 64 KB: [row 256][k 32] per k-sub buffer
  __shared__ __bf16 Bs[4][8192];   // 64 KB: rows 0-127 e0, 128-255 e1
  __shared__ float gS[256 * 8];    // 8 KB
  __shared__ float bS[8 * 128];    // 4 KB

  const int tid = threadIdx.x;
  const int lane = tid & 63;
  const int wv = tid >> 6;     // 0..7
  const int wm = wv >> 1;      // token quarter
  const int wn = wv & 1;       // h half
  const int row0 = blockIdx.x * 256;
  const int col0 = blockIdx.y * 128;

  // Preload gate/be panels (published by phase-0 barrier; read only in EPI).
  for (int i = tid; i < 2048; i += 512) gS[i] = gate[(size_t)row0 * N_E + i];
  for (int i = tid; i < 1024; i += 512)
    bS[i] = be[(size_t)(i >> 7) * N_H + col0 + (i & 127)];

  // Staging: 512 threads x 16B = 8KB per issue; 4 issues per phase:
  // A rows 0-127, A rows 128-255, B e0 rows, B e1 rows (each 256x32 halved).
  const int rA = tid >> 2;           // 0..127
  const int kk = (tid & 3) * 8;
  const __bf16* aB = Xb + (size_t)(row0 + rA) * K_D + kk;
  const __bf16* bB = Wb + (size_t)(col0 + rA) * K_D + kk;

  // Fragment read offsets (within one k-sub buffer).
  const int lr = lane & 15;
  const int lk = (lane >> 4) * 8;
  const int aOff = (wm * 64 + lr) * 32 + lk;
  const int bOff = (wn * 64 + lr) * 32 + lk;

  f32x4 fin[4][4];
#pragma unroll
  for (int m = 0; m < 4; ++m)
#pragma unroll
    for (int h = 0; h < 4; ++h) fin[m][h] = (f32x4){0.f, 0.f, 0.f, 0.f};

  f32x4 acc[4][8];
#pragma unroll
  for (int m = 0; m < 4; ++m)
#pragma unroll
    for (int n = 0; n < 8; ++n) acc[m][n] = (f32x4){0.f, 0.f, 0.f, 0.f};

  // Stage k-sub sn into buffer q. sn = pair*32 + ks; pair stride = 2*N_H*K_D.
  auto STAGE = [&](int sn, int q) {
    const int k0 = (sn & 31) << 5;
    const size_t pOff = (size_t)(sn >> 5) << 22;
    load16_lds(aB + k0, &As[q][tid * 8]);
    load16_lds(aB + (size_t)128 * K_D + k0, &As[q][4096 + tid * 8]);
    load16_lds(bB + pOff + k0, &Bs[q][tid * 8]);
    load16_lds(bB + pOff + (size_t)N_H * K_D + k0, &Bs[q][4096 + tid * 8]);
  };

  // Pair epilogue: fin += g_e0*LR(acc_e0 + be) + g_e1*LR(acc_e1 + be); acc=0.
  auto EPI = [&](int p) {
    const int e0 = p * 2;
#pragma unroll
    for (int m = 0; m < 4; ++m) {
#pragma unroll
      for (int j = 0; j < 4; ++j) {
        const int r = wm * 64 + m * 16 + (lane >> 4) * 4 + j;  // 0..255
        const float g0 = gS[r * 8 + e0];
        const float g1 = gS[r * 8 + e0 + 1];
#pragma unroll
        for (int h = 0; h < 4; ++h) {
          const int c = wn * 64 + h * 16 + lr;                 // 0..127
          float v0 = acc[m][h][j] + bS[e0 * 128 + c];
          v0 = (v0 >= 0.f) ? v0 : 0.01f * v0;
          float v1 = acc[m][4 + h][j] + bS[(e0 + 1) * 128 + c];
          v1 = (v1 >= 0.f) ? v1 : 0.01f * v1;
          fin[m][h][j] += g0 * v0 + g1 * v1;
        }
      }
    }
#pragma unroll
    for (int m = 0; m < 4; ++m)
#pragma unroll
      for (int n = 0; n < 8; ++n) acc[m][n] = (f32x4){0.f, 0.f, 0.f, 0.f};
  };

  // One phase. q = sn&3 (literal at every call site). doStage: sn+2 <= 127.
  auto PHASE = [&](int sn, int q, bool doStage, bool lastPhase) {
    if (lastPhase)
      asm volatile("s_waitcnt vmcnt(0)" ::: "memory");
    else
      asm volatile("s_waitcnt vmcnt(4)" ::: "memory");  // own sn loads landed
    __builtin_amdgcn_s_barrier();        // all waves' sn loads published
    __builtin_amdgcn_sched_barrier(0);   // reads stay below the barrier

    bf16x8 af[4], bfr[8];
#pragma unroll
    for (int m = 0; m < 4; ++m)
      af[m] = *(const bf16x8*)(&As[q][aOff + m * 512]);
#pragma unroll
    for (int n = 0; n < 8; ++n)
      bfr[n] = *(const bf16x8*)(&Bs[q][bOff + ((n >> 2) * 128 + (n & 3) * 16) * 32]);
    asm volatile("s_waitcnt lgkmcnt(0)" ::: "memory");   // frag reads retired
    __builtin_amdgcn_sched_barrier(0);                   // rule 18

    if (doStage) STAGE(sn + 2, (q + 2) & 3);  // target last read at sn-2: safe

    __builtin_amdgcn_s_setprio(1);
#pragma unroll
    for (int n = 0; n < 8; ++n)
#pragma unroll
      for (int m = 0; m < 4; ++m)
        acc[m][n] = mfma16(af[m], bfr[n], acc[m][n]);
    __builtin_amdgcn_s_setprio(0);

    if ((sn & 31) == 31) EPI(sn >> 5);
  };

  STAGE(0, 0);
  STAGE(1, 1);  // 8 own loads in flight; phase 0 waits vmcnt(4)

#pragma unroll 1
  for (int t4 = 0; t4 < 31; ++t4) {
    const int sn = t4 * 4;
    PHASE(sn + 0, 0, true, false);
    PHASE(sn + 1, 1, true, false);
    PHASE(sn + 2, 2, true, false);
    PHASE(sn + 3, 3, true, false);
  }
  PHASE(124, 0, true, false);   // stages 126
  PHASE(125, 1, true, false);   // stages 127
  PHASE(126, 2, false, false);  // vmcnt(4): 126 landed, 127 in flight
  PHASE(127, 3, false, true);   // vmcnt(0) + EPI(3)

  // C write (fp32 out)
#pragma unroll
  for (int m = 0; m < 4; ++m) {
#pragma unroll
    for (int j = 0; j < 4; ++j) {
      const size_t r = (size_t)(row0 + wm * 64 + m * 16 + (lane >> 4) * 4 + j);
#pragma unroll
      for (int h = 0; h < 4; ++h) {
        out[r * N_H + col0 + wn * 64 + h * 16 + lr] = fin[m][h][j];
      }
    }
  }
}

extern "C" void kernel_launch(void* const* d_in, const int* in_sizes, int n_in,
                              void* d_out, int out_size, void* d_ws, size_t ws_size,
                              hipStream_t stream) {
  const float* X  = (const float*)d_in[0];  // [8192,1024]
  const float* Wg = (const float*)d_in[1];  // [8,1024]
  const float* bg = (const float*)d_in[2];  // [8]
  const float* We = (const float*)d_in[3];  // [8,2048,1024]
  const float* be = (const float*)d_in[4];  // [8,2048]
  float* out = (float*)d_out;               // [8192,2048]

  // Workspace layout
  char* ws = (char*)d_ws;
  __bf16* Xb   = (__bf16*)(ws);                               // 16 MB
  __bf16* Wb   = (__bf16*)(ws + (size_t)16 * 1024 * 1024);    // 32 MB
  float*  gate = (float*)(ws + (size_t)48 * 1024 * 1024);     // 256 KB

  // 1) We f32 -> bf16
  cvt_kernel<<<2048, 256, 0, stream>>>(We, Wb, (N_E * N_H * K_D) / 4);

  // 2) gate probs + X f32->bf16 (fused)
  gate_kernel<<<M_TOK / 4, 256, 0, stream>>>(X, Wg, bg, gate, Xb);

  // 3) fused expert GEMM + gate-weighted reduction
  dim3 grid(M_TOK / 256, N_H / 128);
  moe_main<<<grid, 512, 0, stream>>>(Xb, Wb, gate, be, out);
}